// Round 10
// baseline (154.075 us; speedup 1.0000x reference)
//
#include <hip/hip_runtime.h>
#include <math.h>

#define KNN 16
#define NPTS 8192
#define PTCH 256
#define NPATCH 32
#define NBATCH 4
#define CAP 16           // per-lane survivor list capacity (overflow -> exact fallback)
#define LAMBDA_T 64.0f   // target E[survivors]/query

// spatial grid
#define NC 16
#define NCELLS (NC * NC * NC)
#define GMIN -4.2f
#define ICS 1.9047619f   // 1 / 0.525 ; NC*0.525 = 8.4 spans [-4.2, 4.2]

// E[#points within distance s of a query at radius r], N iid N(0,I3). fp32.
// Heuristic only: exactness guaranteed by margin check + fallback.
__device__ __forceinline__ float lam_f(float r, float s)
{
    const float C     = 0.063493636f;    // (2*pi)^{-3/2}
    const float SQ2PI = 2.5066283f;
    const float IS2   = 0.70710678f;
    float a = fabsf(r - s), b = r + s;
    float amr = a - r;
    float coefA = amr * amr + 2.f - s * s;
    float I = 2.f * __expf(-0.5f * b * b) - coefA * __expf(-0.5f * a * a)
            + r * SQ2PI * (erff(b * IS2) - erff(a * IS2));
    float M = C * (3.14159265f / r) * I;
    if (s > r) {
        float u = s - r;
        M += 12.566371f * C * (1.2533141f * erff(u * IS2) - u * __expf(-0.5f * u * u));
    }
    return (float)NPTS * M;
}

// ---------- fp64 cyclic Jacobi 3x3 (verified) ----------
__device__ __forceinline__ void jrot(double& app, double& aqq, double& apq,
                                     double& arp, double& arq,
                                     double& vp0, double& vq0,
                                     double& vp1, double& vq1,
                                     double& vp2, double& vq2)
{
    double g = apq;
    if (g == 0.0) return;
    double theta = (aqq - app) / (2.0 * g);
    double at = fabs(theta);
    double t = (at > 1.0e154) ? (0.5 / theta)
                              : (copysign(1.0, theta) / (at + sqrt(theta * theta + 1.0)));
    double c = 1.0 / sqrt(t * t + 1.0);
    double s = t * c;
    double tau = s / (1.0 + c);
    app -= t * g;
    aqq += t * g;
    apq = 0.0;
    double rp = arp, rq = arq;
    arp = rp - s * (rq + tau * rp);
    arq = rq + s * (rp - tau * rq);
    double p0 = vp0, q0 = vq0;
    vp0 = p0 - s * (q0 + tau * p0); vq0 = q0 + s * (p0 - tau * q0);
    double p1 = vp1, q1 = vq1;
    vp1 = p1 - s * (q1 + tau * p1); vq1 = q1 + s * (p1 - tau * q1);
    double p2 = vp2, q2 = vq2;
    vp2 = p2 - s * (q2 + tau * p2); vq2 = q2 + s * (p2 - tau * q2);
}

__device__ __forceinline__ void eig3(double a00, double a11, double a22,
                                     double a01, double a02, double a12,
                                     double& nx, double& ny, double& nz,
                                     double& lmin, double& lsum)
{
    double v00 = 1, v01 = 0, v02 = 0;
    double v10 = 0, v11 = 1, v12 = 0;
    double v20 = 0, v21 = 0, v22 = 1;
    double scale = fabs(a00) + fabs(a11) + fabs(a22) + fabs(a01) + fabs(a02) + fabs(a12);
    if (scale > 0.0) {
        for (int sweep = 0; sweep < 6; ++sweep) {
            double off = fabs(a01) + fabs(a02) + fabs(a12);
            if (off <= scale * 1e-15) break;
            jrot(a00, a11, a01, a02, a12, v00, v01, v10, v11, v20, v21);
            jrot(a00, a22, a02, a01, a12, v00, v02, v10, v12, v20, v22);
            jrot(a11, a22, a12, a01, a02, v01, v02, v11, v12, v21, v22);
        }
    }
    lsum = a00 + a11 + a22;
    lmin = a00; nx = v00; ny = v10; nz = v20;
    if (a11 < lmin) { lmin = a11; nx = v01; ny = v11; nz = v21; }
    if (a22 < lmin) { lmin = a22; nx = v02; ny = v12; nz = v22; }
}

// u32 key: (d2 float bits, low 13 mantissa bits cleared) | idx(13b). Ties -> lower idx.
__device__ __forceinline__ unsigned mkkey(float d2, unsigned idx) {
    return (__float_as_uint(d2) & 0xFFFFE000u) | idx;
}

// Caller guarantees key < L[15]. Sorted-ascending bubble (v_min/v_max pairs).
__device__ __forceinline__ void insert16(unsigned key, unsigned* L)
{
    L[KNN - 1] = key;
    #pragma unroll
    for (int m = KNN - 1; m >= 1; --m) {
        unsigned a = L[m - 1], b = L[m];
        L[m - 1] = min(a, b);
        L[m]     = max(a, b);
    }
}

// Snapshot-based butterfly merge of sorted 16-lists across lanes h = lane&3.
__device__ __forceinline__ void merge4(unsigned* L, int lane)
{
    #pragma unroll
    for (int step = 1; step <= 2; step <<= 1) {
        unsigned tmp[KNN];
        #pragma unroll
        for (int m = 0; m < KNN; ++m) tmp[m] = __shfl(L[m], lane ^ step, 64);
        for (int m = 0; m < KNN; ++m) {
            if (tmp[m] >= L[KNN - 1]) break;
            insert16(tmp[m], L);
        }
    }
}

__device__ __forceinline__ unsigned mbcnt64(unsigned long long m) {
    return __builtin_amdgcn_mbcnt_hi((unsigned)(m >> 32),
           __builtin_amdgcn_mbcnt_lo((unsigned)m, 0u));
}

// ---------- grid build ----------
__device__ __forceinline__ int cidx(float v) {
    int i = (int)floorf((v - GMIN) * ICS);
    return min(max(i, 0), NC - 1);
}
__device__ __forceinline__ int cellOf(float x, float y, float z) {
    return (cidx(z) * NC + cidx(y)) * NC + cidx(x);
}

// One block per batch: zero out + histogram + scan + scatter, all in LDS.
#define BT 1024
__global__ void __launch_bounds__(1024)
build_kernel(const float* __restrict__ pts, float* __restrict__ out,
             unsigned* __restrict__ cellStart, float4* __restrict__ sorted)
{
    __shared__ unsigned hist[NCELLS];     // 16 KB; reused as cellPos after scan
    __shared__ unsigned part[BT];         // 4 KB
    const int b = blockIdx.x;
    const int t = threadIdx.x;
    if (b == 0 && t == 0) { out[0] = 0.0f; out[1] = 0.0f; }
    for (int i = t; i < NCELLS; i += BT) hist[i] = 0u;
    __syncthreads();
    const float* base = pts + (size_t)b * (NPTS * 3);
    float px[8], py[8], pz[8];
    int pc[8];
    #pragma unroll
    for (int k = 0; k < 8; ++k) {
        int i = k * BT + t;
        px[k] = base[i * 3 + 0];
        py[k] = base[i * 3 + 1];
        pz[k] = base[i * 3 + 2];
        pc[k] = cellOf(px[k], py[k], pz[k]);
        atomicAdd(&hist[pc[k]], 1u);
    }
    __syncthreads();
    // scan: thread t owns cells t*4 .. t*4+3
    unsigned loc[4], s = 0;
    #pragma unroll
    for (int i = 0; i < 4; ++i) { loc[i] = s; s += hist[t * 4 + i]; }
    part[t] = s;
    __syncthreads();
    for (int o = 1; o < BT; o <<= 1) {
        unsigned u = (t >= o) ? part[t - o] : 0u;
        __syncthreads();
        part[t] += u;
        __syncthreads();
    }
    unsigned basex = part[t] - s;   // exclusive prefix of this thread's 4-cell chunk
    unsigned* csb = cellStart + b * (NCELLS + 1);
    #pragma unroll
    for (int i = 0; i < 4; ++i) {
        unsigned e = basex + loc[i];
        csb[t * 4 + i] = e;
        hist[t * 4 + i] = e;        // becomes running cell position
    }
    if (t == BT - 1) csb[NCELLS] = basex + s;   // == NPTS
    __syncthreads();
    float4* sb = sorted + (size_t)b * NPTS;
    #pragma unroll
    for (int k = 0; k < 8; ++k) {
        int i = k * BT + t;
        unsigned slot = atomicAdd(&hist[pc[k]], 1u);
        float4 v;
        v.x = px[k]; v.y = py[k]; v.z = pz[k]; v.w = __uint_as_float((unsigned)i);
        sb[slot] = v;
    }
}

// One THREAD per query: 32768 gate bisections fully SIMT-parallel.
__global__ void __launch_bounds__(256)
gate_kernel(const float* __restrict__ pts, float* __restrict__ g2buf)
{
    int q = blockIdx.x * 256 + threadIdx.x;     // 0..32767
    int b = q >> 13, i = q & (NPTS - 1);
    const float* pp = pts + (size_t)b * (NPTS * 3) + (size_t)i * 3;
    float x = pp[0], y = pp[1], z = pp[2];
    float r = fmaxf(sqrtf(x * x + y * y + z * z), 0.01f);
    float lo = 0.f, hi = 12.f;
    #pragma unroll 1
    for (int it = 0; it < 16; ++it) {
        float mid = 0.5f * (lo + hi);
        if (lam_f(r, mid) < LAMBDA_T) lo = mid; else hi = mid;
    }
    g2buf[q] = hi * hi;
}

// R10 fused filter+select, BALLOT-FREE hot loop. One WAVE per query.
// R9's inner loop had __any (break) + __ballot + mbcnt + serial wave-count per
// 64 candidates -- a ~4-deep cross-lane dependent chain that blocked load
// pipelining (fselect 55us, VALUBusy 50%, HBM 1.5%). Now: per row-group the
// trip count is fixed (shfl_xor max over sub-group lens), and each lane
// appends survivors to its OWN LDS list (lb[lane*CAP], private counter).
// Per candidate: load + 3 FMA + cmp + predicated ds_write. Zero cross-lane ops.
// One prefix-sum (6 shfl_up) at the end compacts lists for the radix select.
// Key MULTISET is unchanged (order irrelevant: radix+rank-sort output is
// ascending by key) -> idx16 bit-identical. valid additionally requires
// all(lc <= CAP); overflow -> exact lane-0 fallback (P ~ 1e-12).
__global__ void __launch_bounds__(256)
fselect_kernel(const float* __restrict__ pts, const float* __restrict__ g2buf,
               const unsigned* __restrict__ cellStart,
               const float4* __restrict__ sortedp,
               unsigned* __restrict__ idx16)
{
    __shared__ unsigned lanebuf[4 * 64 * CAP];   // 16 KB: per-lane survivor lists
    __shared__ unsigned survl[4 * 128];          // 2 KB: compacted keys for radix
    const int t = threadIdx.x;
    const int wv = t >> 6;
    const int lane = t & 63;
    const int wq = __builtin_amdgcn_readfirstlane(blockIdx.x * 4 + wv);  // query id
    const int b  = wq >> 13;
    const int qi = wq & (NPTS - 1);
    const float* base = pts + (size_t)b * (NPTS * 3);
    const unsigned* cs = cellStart + b * (NCELLS + 1);
    const float4* sp = sortedp + (size_t)b * NPTS;
    unsigned* lb = lanebuf + (unsigned)(wv * 64 + lane) * CAP;
    unsigned* sl = survl + wv * 128;

    const float qx = base[qi * 3 + 0];   // wave-uniform scalar loads
    const float qy = base[qi * 3 + 1];
    const float qz = base[qi * 3 + 2];
    const float g2 = g2buf[wq];
    const float g  = sqrtf(g2);

    int ixlo = cidx(qx - g), ixhi = cidx(qx + g);
    int iylo = cidx(qy - g), iyhi = cidx(qy + g);
    int izlo = cidx(qz - g), izhi = cidx(qz + g);
    int nx = ixhi - ixlo + 1;
    int ny = iyhi - iylo + 1;
    int nyz = ny * (izhi - izlo + 1);
    const int lR  = (nyz >= 8) ? 3 : (nyz >= 4) ? 2 : (nyz >= 2) ? 1 : 0;
    const int R   = 1 << lR;
    const int lsl = 6 - lR;
    const unsigned SL = 64u >> lR;
    const unsigned slot = (unsigned)lane & (SL - 1u);
    unsigned lc = 0;                           // PRIVATE per-lane survivor count
    #pragma unroll 1
    for (int r0 = 0; r0 < nyz; r0 += 64) {
        int r = r0 + lane;
        unsigned pk = 0;
        if (r < nyz) {
            int iz = izlo + r / ny;
            int iy = iylo + (r - (r / ny) * ny);
            int cb = (iz * NC + iy) * NC + ixlo;
            unsigned sB = cs[cb];
            pk = sB | ((cs[cb + nx] - sB) << 14);
        }
        int rmax = min(nyz - r0, 64);
        int gcount = (rmax + R - 1) >> lR;
        #pragma unroll 1
        for (int gg = 0; gg < gcount; ++gg) {
            unsigned pkm = __shfl(pk, (gg << lR) + (lane >> lsl), 64);
            unsigned sBm = pkm & 0x3FFFu;
            unsigned lm  = pkm >> 14;
            // fixed trip count: max row len across this group's sub-rows
            unsigned mx = lm;
            #pragma unroll 1
            for (int o = (int)SL; o < 64; o <<= 1)
                mx = max(mx, (unsigned)__shfl_xor((int)mx, o, 64));
            int trips = __builtin_amdgcn_readfirstlane((int)((mx + SL - 1) >> lsl));
            unsigned st = slot;
            #pragma unroll 1
            for (int tt = 0; tt < trips; ++tt, st += SL) {
                bool in = st < lm;
                float4 c = sp[min(sBm + st, (unsigned)(NPTS - 1))];
                float dx = qx - c.x, dy = qy - c.y, dz = qz - c.z;
                float d2 = dx * dx + dy * dy + dz * dz;   // reference-form d2
                if (in && (d2 < g2)) {                    // no cross-lane ops
                    if (lc < CAP) lb[lc] = mkkey(d2, __float_as_uint(c.w));
                    lc++;
                }
            }
        }
    }

    // ---- one-shot compaction + in-wave top-16 selection ----
    unsigned pre = lc;
    #pragma unroll
    for (int o = 1; o < 64; o <<= 1) {
        unsigned v = __shfl_up(pre, o, 64);
        if (lane >= o) pre += v;
    }
    unsigned cnt = __shfl(pre, 63, 64);        // total survivors (wave-uniform)
    unsigned ex  = pre - lc;                   // exclusive prefix
    bool over = __any((lc > CAP) ? 1 : 0);
    bool valid = (cnt >= KNN) && (cnt <= 128u) && !over;
    if (valid) {
        #pragma unroll 1
        for (unsigned m = 0; m < lc; ++m) sl[ex + m] = lb[m];
        unsigned k0 = (lane < (int)cnt)      ? sl[lane]      : 0xFFFFFFFFu;
        unsigned k1 = (lane + 64 < (int)cnt) ? sl[lane + 64] : 0xFFFFFFFFu;
        // radix binary search: P ends as the exact 16th-smallest key
        unsigned P = 0;
        #pragma unroll 1
        for (int bit = 31; bit >= 0; --bit) {
            unsigned mid = P | (1u << bit);
            unsigned c = (unsigned)__popcll(__ballot(k0 < mid))
                       + (unsigned)__popcll(__ballot(k1 < mid));
            if (c < 16u) P = mid;      // 16th smallest >= mid
        }
        // margin check: all filtered-out points provably outside 16th bucket
        float upper = __uint_as_float((P & 0xFFFFE000u) + 0x2000u);
        valid = (upper < g2 * 0.999f - 1e-5f);
        if (valid) {
            bool sel0 = (k0 <= P);
            bool sel1 = (k1 <= P);
            unsigned long long m0 = __ballot(sel0);
            unsigned long long m1 = __ballot(sel1);
            unsigned base1 = (unsigned)__popcll(m0);
            if (sel0) sl[mbcnt64(m0)] = k0;           // exactly 16 selected total
            if (sel1) sl[base1 + mbcnt64(m1)] = k1;
            unsigned myk = sl[lane & 15];             // lanes 0-15 meaningful
            unsigned rnk = 0;
            #pragma unroll
            for (int j = 0; j < 16; ++j) {
                unsigned kj = __shfl(myk, j, 64);
                rnk += (kj < myk) ? 1u : 0u;
            }
            if (lane < 16)
                idx16[(size_t)wq * 32 + rnk] = myk & 0x1FFFu;   // ascending order
        }
    }
    if (!valid && lane == 0) {       // exact fallback (P ~ 1e-12/query)
        unsigned gl[KNN];
        #pragma unroll
        for (int m = 0; m < KNN; ++m) gl[m] = 0xFFFFFFFFu;
        #pragma unroll 1
        for (int i = 0; i < NPTS; ++i) {
            float cx = base[i * 3 + 0];
            float cy = base[i * 3 + 1];
            float cz = base[i * 3 + 2];
            float dx = qx - cx, dy = qy - cy, dz = qz - cz;
            float d2 = dx * dx + dy * dy + dz * dz;
            unsigned k = mkkey(d2, (unsigned)i);
            if (k < gl[KNN - 1]) insert16(k, gl);
        }
        unsigned* dst = idx16 + (size_t)wq * 32;
        #pragma unroll
        for (int m = 0; m < KNN; ++m) dst[m] = gl[m] & 0x1FFFu;
    }
}

// Patch kNN: 64 queries/block (quarter patch), 4 lanes/query x 64 patch pts,
// gated bubble insert + butterfly merge4 (verbatim).
__global__ void __launch_bounds__(256)
pselect_kernel(const float* __restrict__ pts, unsigned* __restrict__ idx16)
{
    __shared__ float4 pbuf4[PTCH];                 // 4 KB own patch
    const int t = threadIdx.x;
    const int w = t >> 6;
    const int lane = t & 63;
    const int p = blockIdx.x;
    const int quarter = blockIdx.y;
    const int b = blockIdx.z;
    const float* base = pts + (size_t)b * (NPTS * 3);

    {
        const float* src = base + p * (PTCH * 3);
        float* dst = (float*)pbuf4;
        #pragma unroll
        for (int s = 0; s < 3; ++s) {
            int f = t + s * 256;
            int j = f / 3;
            int c = f - 3 * j;
            dst[j * 4 + c] = src[f];
        }
    }
    __syncthreads();

    const int qq = lane >> 2;            // 0..15
    const int h = lane & 3;
    const int qlocal = quarter * 64 + w * 16 + qq;   // 0..255 within patch
    float4 qv = pbuf4[qlocal];
    const float pqx = qv.x, pqy = qv.y, pqz = qv.z;

    unsigned pl[KNN];
    #pragma unroll
    for (int m = 0; m < KNN; ++m) pl[m] = 0xFFFFFFFFu;
    const int j0 = h * 64;
    #pragma unroll 4
    for (int j = j0; j < j0 + 64; ++j) {
        float4 c = pbuf4[j];
        float dx = pqx - c.x, dy = pqy - c.y, dz = pqz - c.z;
        float d2 = dx * dx + dy * dy + dz * dz;
        unsigned k = mkkey(d2, (unsigned)j);
        if (k < pl[KNN - 1]) insert16(k, pl);
    }
    merge4(pl, lane);
    if (h == 0) {
        int qid = b * NPTS + p * PTCH + qlocal;
        unsigned* dst = idx16 + (size_t)qid * 32 + 16;   // type 1 = patch
        #pragma unroll
        for (int m = 0; m < KNN; ++m)
            dst[m] = (unsigned)(p * PTCH) + (pl[m] & 0x1FFFu);
    }
}

// 1 thread per eig (65536 = 32768 queries x {global,patch}); full-lane fp64.
__global__ void __launch_bounds__(256)
eig_loss_kernel(const float* __restrict__ pts,
                const unsigned* __restrict__ idx16,
                double* __restrict__ partials)
{
    __shared__ double sln[4], slv[4];
    const int t = threadIdx.x;
    const int e = blockIdx.x * 256 + t;     // 0..65535
    const int qid = e >> 1;
    const int b = qid >> 13;
    const int qi = qid & (NPTS - 1);
    const float* base = pts + (size_t)b * (NPTS * 3);

    const double qxd = (double)base[qi * 3 + 0];
    const double qyd = (double)base[qi * 3 + 1];
    const double qzd = (double)base[qi * 3 + 2];

    const unsigned* L = idx16 + (size_t)qid * 32 + (e & 1) * 16;
    double c00 = 0, c11 = 0, c22 = 0, c01 = 0, c02 = 0, c12 = 0;
    #pragma unroll
    for (int m = 0; m < KNN; ++m) {
        int idx = (int)L[m];
        double dx = (double)base[idx * 3 + 0] - qxd;
        double dy = (double)base[idx * 3 + 1] - qyd;
        double dz = (double)base[idx * 3 + 2] - qzd;
        c00 += dx * dx; c11 += dy * dy; c22 += dz * dz;
        c01 += dx * dy; c02 += dx * dz; c12 += dy * dz;
    }
    double nx, ny, nz, lmin, lsum;
    eig3(c00, c11, c22, c01, c02, c12, nx, ny, nz, lmin, lsum);
    double sv = lmin / lsum;

    double onx = __shfl_xor(nx, 1, 64);
    double ony = __shfl_xor(ny, 1, 64);
    double onz = __shfl_xor(nz, 1, 64);
    double osv = __shfl_xor(sv, 1, 64);

    double ln = 0.0, lsv = 0.0;
    if ((e & 1) == 0) {          // even lane: own = global, partner = patch
        double dx = fabs(onx) - fabs(nx);
        double dy = fabs(ony) - fabs(ny);
        double dz = fabs(onz) - fabs(nz);
        ln  = sqrt(dx * dx + dy * dy + dz * dz);
        double ds = osv - sv;
        lsv = ds * ds;
    }
    #pragma unroll
    for (int o = 32; o > 0; o >>= 1) {
        ln  += __shfl_down(ln, o);
        lsv += __shfl_down(lsv, o);
    }
    const int w = t >> 6;
    if ((t & 63) == 0) { sln[w] = ln; slv[w] = lsv; }
    __syncthreads();
    if (t == 0) {
        partials[blockIdx.x * 2 + 0] = sln[0] + sln[1] + sln[2] + sln[3];
        partials[blockIdx.x * 2 + 1] = slv[0] + slv[1] + slv[2] + slv[3];
    }
}

// 1 block: deterministic fixed-order double sum of 256 partial pairs.
__global__ void __launch_bounds__(256)
reduce_kernel(const double* __restrict__ partials, float* __restrict__ out)
{
    __shared__ double sln[4], slv[4];
    const int t = threadIdx.x;
    double a = partials[t * 2 + 0];
    double c = partials[t * 2 + 1];
    #pragma unroll
    for (int o = 32; o > 0; o >>= 1) {
        a += __shfl_down(a, o);
        c += __shfl_down(c, o);
    }
    if ((t & 63) == 0) { sln[t >> 6] = a; slv[t >> 6] = c; }
    __syncthreads();
    if (t == 0) {
        const double inv = 1.0 / (double)(NBATCH * NPTS);
        out[0] = (float)((sln[0] + sln[1] + sln[2] + sln[3]) * inv);
        out[1] = (float)((slv[0] + slv[1] + slv[2] + slv[3]) * inv);
    }
}

extern "C" void kernel_launch(void* const* d_in, const int* in_sizes, int n_in,
                              void* d_out, int out_size, void* d_ws, size_t ws_size,
                              hipStream_t stream)
{
    const float* pts = (const float*)d_in[0];
    float* out = (float*)d_out;

    // workspace carve-up (16B-aligned), ~4.9 MB total:
    //   cellStart @ 0       : 4*4097*4   = 65552
    //   sorted    @ 65552   : 4*8192*16  = 524288  -> 589840
    //   g2buf     @ 589840  : 32768*4    = 131072  -> 720912
    //   idx16     @ 720912  : 32768*32*4 = 4194304 -> 4915216
    //   partials  @ 4915216 : 256*2*8    = 4096    -> 4919312
    unsigned char* ws = (unsigned char*)d_ws;
    unsigned* cellStart = (unsigned*)(ws);
    float4*   sorted    = (float4*)  (ws + 65552);
    float*    g2buf     = (float*)   (ws + 589840);
    unsigned* idx16     = (unsigned*)(ws + 720912);
    double*   partials  = (double*)  (ws + 4915216);

    hipLaunchKernelGGL(build_kernel, dim3(NBATCH), dim3(BT), 0, stream,
                       pts, out, cellStart, sorted);
    hipLaunchKernelGGL(gate_kernel, dim3(NBATCH * NPTS / 256), dim3(256), 0, stream,
                       pts, g2buf);
    hipLaunchKernelGGL(fselect_kernel, dim3(NBATCH * NPTS / 4), dim3(256), 0, stream,
                       pts, g2buf, cellStart, sorted, idx16);
    hipLaunchKernelGGL(pselect_kernel, dim3(NPATCH, 4, NBATCH), dim3(256), 0, stream,
                       pts, idx16);
    hipLaunchKernelGGL(eig_loss_kernel, dim3(NBATCH * NPTS * 2 / 256), dim3(256),
                       0, stream, pts, idx16, partials);
    hipLaunchKernelGGL(reduce_kernel, dim3(1), dim3(256), 0, stream,
                       partials, out);
}

// Round 13
// 146.363 us; speedup vs baseline: 1.0527x; 1.0527x over previous
//
#include <hip/hip_runtime.h>
#include <math.h>

#define KNN 16
#define NPTS 8192
#define PTCH 256
#define NPATCH 32
#define NBATCH 4
#define SSTRIDE 130      // survivor slots/query (mean 48 now, huge headroom)
#define LAMBDA_T 48.0f   // target E[survivors]/query (64->48: -25% stream work;
                         // fallback risk ~1.3e-3/run, deterministic input)

// spatial grid
#define NC 16
#define NCELLS (NC * NC * NC)
#define GMIN -4.2f
#define ICS 1.9047619f   // 1 / 0.525 ; NC*0.525 = 8.4 spans [-4.2, 4.2]

// E[#points within distance s of a query at radius r], N iid N(0,I3). fp32.
// Heuristic only: exactness guaranteed by margin check + fallback.
__device__ __forceinline__ float lam_f(float r, float s)
{
    const float C     = 0.063493636f;    // (2*pi)^{-3/2}
    const float SQ2PI = 2.5066283f;
    const float IS2   = 0.70710678f;
    float a = fabsf(r - s), b = r + s;
    float amr = a - r;
    float coefA = amr * amr + 2.f - s * s;
    float I = 2.f * __expf(-0.5f * b * b) - coefA * __expf(-0.5f * a * a)
            + r * SQ2PI * (erff(b * IS2) - erff(a * IS2));
    float M = C * (3.14159265f / r) * I;
    if (s > r) {
        float u = s - r;
        M += 12.566371f * C * (1.2533141f * erff(u * IS2) - u * __expf(-0.5f * u * u));
    }
    return (float)NPTS * M;
}

// ---------- fp64 cyclic Jacobi 3x3 (verified) ----------
__device__ __forceinline__ void jrot(double& app, double& aqq, double& apq,
                                     double& arp, double& arq,
                                     double& vp0, double& vq0,
                                     double& vp1, double& vq1,
                                     double& vp2, double& vq2)
{
    double g = apq;
    if (g == 0.0) return;
    double theta = (aqq - app) / (2.0 * g);
    double at = fabs(theta);
    double t = (at > 1.0e154) ? (0.5 / theta)
                              : (copysign(1.0, theta) / (at + sqrt(theta * theta + 1.0)));
    double c = 1.0 / sqrt(t * t + 1.0);
    double s = t * c;
    double tau = s / (1.0 + c);
    app -= t * g;
    aqq += t * g;
    apq = 0.0;
    double rp = arp, rq = arq;
    arp = rp - s * (rq + tau * rp);
    arq = rq + s * (rp - tau * rq);
    double p0 = vp0, q0 = vq0;
    vp0 = p0 - s * (q0 + tau * p0); vq0 = q0 + s * (p0 - tau * q0);
    double p1 = vp1, q1 = vq1;
    vp1 = p1 - s * (q1 + tau * p1); vq1 = q1 + s * (p1 - tau * q1);
    double p2 = vp2, q2 = vq2;
    vp2 = p2 - s * (q2 + tau * p2); vq2 = q2 + s * (p2 - tau * q2);
}

__device__ __forceinline__ void eig3(double a00, double a11, double a22,
                                     double a01, double a02, double a12,
                                     double& nx, double& ny, double& nz,
                                     double& lmin, double& lsum)
{
    double v00 = 1, v01 = 0, v02 = 0;
    double v10 = 0, v11 = 1, v12 = 0;
    double v20 = 0, v21 = 0, v22 = 1;
    double scale = fabs(a00) + fabs(a11) + fabs(a22) + fabs(a01) + fabs(a02) + fabs(a12);
    if (scale > 0.0) {
        for (int sweep = 0; sweep < 6; ++sweep) {
            double off = fabs(a01) + fabs(a02) + fabs(a12);
            if (off <= scale * 1e-15) break;
            jrot(a00, a11, a01, a02, a12, v00, v01, v10, v11, v20, v21);
            jrot(a00, a22, a02, a01, a12, v00, v02, v10, v12, v20, v22);
            jrot(a11, a22, a12, a01, a02, v01, v02, v11, v12, v21, v22);
        }
    }
    lsum = a00 + a11 + a22;
    lmin = a00; nx = v00; ny = v10; nz = v20;
    if (a11 < lmin) { lmin = a11; nx = v01; ny = v11; nz = v21; }
    if (a22 < lmin) { lmin = a22; nx = v02; ny = v12; nz = v22; }
}

// u32 key: (d2 float bits, low 13 mantissa bits cleared) | idx(13b). Ties -> lower idx.
__device__ __forceinline__ unsigned mkkey(float d2, unsigned idx) {
    return (__float_as_uint(d2) & 0xFFFFE000u) | idx;
}

// Caller guarantees key < L[15]. Sorted-ascending bubble (v_min/v_max pairs).
__device__ __forceinline__ void insert16(unsigned key, unsigned* L)
{
    L[KNN - 1] = key;
    #pragma unroll
    for (int m = KNN - 1; m >= 1; --m) {
        unsigned a = L[m - 1], b = L[m];
        L[m - 1] = min(a, b);
        L[m]     = max(a, b);
    }
}

// Snapshot-based butterfly merge of sorted 16-lists across lanes h = lane&3.
__device__ __forceinline__ void merge4(unsigned* L, int lane)
{
    #pragma unroll
    for (int step = 1; step <= 2; step <<= 1) {
        unsigned tmp[KNN];
        #pragma unroll
        for (int m = 0; m < KNN; ++m) tmp[m] = __shfl(L[m], lane ^ step, 64);
        for (int m = 0; m < KNN; ++m) {
            if (tmp[m] >= L[KNN - 1]) break;
            insert16(tmp[m], L);
        }
    }
}

__device__ __forceinline__ unsigned mbcnt64(unsigned long long m) {
    return __builtin_amdgcn_mbcnt_hi((unsigned)(m >> 32),
           __builtin_amdgcn_mbcnt_lo((unsigned)m, 0u));
}

// ---------- grid build ----------
__device__ __forceinline__ int cidx(float v) {
    int i = (int)floorf((v - GMIN) * ICS);
    return min(max(i, 0), NC - 1);
}
__device__ __forceinline__ int cellOf(float x, float y, float z) {
    return (cidx(z) * NC + cidx(y)) * NC + cidx(x);
}

// One block per batch: zero out + histogram + scan + scatter, all in LDS.
#define BT 1024
__global__ void __launch_bounds__(1024)
build_kernel(const float* __restrict__ pts, float* __restrict__ out,
             unsigned* __restrict__ cellStart, float4* __restrict__ sorted)
{
    __shared__ unsigned hist[NCELLS];     // 16 KB; reused as cellPos after scan
    __shared__ unsigned part[BT];         // 4 KB
    const int b = blockIdx.x;
    const int t = threadIdx.x;
    if (b == 0 && t == 0) { out[0] = 0.0f; out[1] = 0.0f; }
    for (int i = t; i < NCELLS; i += BT) hist[i] = 0u;
    __syncthreads();
    const float* base = pts + (size_t)b * (NPTS * 3);
    float px[8], py[8], pz[8];
    int pc[8];
    #pragma unroll
    for (int k = 0; k < 8; ++k) {
        int i = k * BT + t;
        px[k] = base[i * 3 + 0];
        py[k] = base[i * 3 + 1];
        pz[k] = base[i * 3 + 2];
        pc[k] = cellOf(px[k], py[k], pz[k]);
        atomicAdd(&hist[pc[k]], 1u);
    }
    __syncthreads();
    // scan: thread t owns cells t*4 .. t*4+3
    unsigned loc[4], s = 0;
    #pragma unroll
    for (int i = 0; i < 4; ++i) { loc[i] = s; s += hist[t * 4 + i]; }
    part[t] = s;
    __syncthreads();
    for (int o = 1; o < BT; o <<= 1) {
        unsigned u = (t >= o) ? part[t - o] : 0u;
        __syncthreads();
        part[t] += u;
        __syncthreads();
    }
    unsigned basex = part[t] - s;   // exclusive prefix of this thread's 4-cell chunk
    unsigned* csb = cellStart + b * (NCELLS + 1);
    #pragma unroll
    for (int i = 0; i < 4; ++i) {
        unsigned e = basex + loc[i];
        csb[t * 4 + i] = e;
        hist[t * 4 + i] = e;        // becomes running cell position
    }
    if (t == BT - 1) csb[NCELLS] = basex + s;   // == NPTS
    __syncthreads();
    float4* sb = sorted + (size_t)b * NPTS;
    #pragma unroll
    for (int k = 0; k < 8; ++k) {
        int i = k * BT + t;
        unsigned slot = atomicAdd(&hist[pc[k]], 1u);
        float4 v;
        v.x = px[k]; v.y = py[k]; v.z = pz[k]; v.w = __uint_as_float((unsigned)i);
        sb[slot] = v;
    }
}

// One THREAD per query: 32768 gate bisections fully SIMT-parallel.
__global__ void __launch_bounds__(256)
gate_kernel(const float* __restrict__ pts, float* __restrict__ g2buf)
{
    int q = blockIdx.x * 256 + threadIdx.x;     // 0..32767
    int b = q >> 13, i = q & (NPTS - 1);
    const float* pp = pts + (size_t)b * (NPTS * 3) + (size_t)i * 3;
    float x = pp[0], y = pp[1], z = pp[2];
    float r = fmaxf(sqrtf(x * x + y * y + z * z), 0.01f);
    float lo = 0.f, hi = 12.f;
    #pragma unroll 1
    for (int it = 0; it < 16; ++it) {
        float mid = 0.5f * (lo + hi);
        if (lam_f(r, mid) < LAMBDA_T) lo = mid; else hi = mid;
    }
    g2buf[q] = hi * hi;
}

// Fused filter+select (R9 loop verbatim -- ran clean at lambda=64, 151.4us
// total). One WAVE per query: stream candidates (row x slot), survivors ->
// LDS; 32-step radix binary-search finds the exact 16th-smallest key P;
// ballot-compact + 16-shfl rank sort emits the 16 global indices ascending --
// bit-identical to the insert16/merge4 path. Margin check on P + lane-0 exact
// fallback preserve exactness at any lambda.
__global__ void __launch_bounds__(256)
fselect_kernel(const float* __restrict__ pts, const float* __restrict__ g2buf,
               const unsigned* __restrict__ cellStart,
               const float4* __restrict__ sortedp,
               unsigned* __restrict__ idx16)
{
    __shared__ unsigned survl[4 * SSTRIDE];   // 2 KB: 4 queries/block
    const int t = threadIdx.x;
    const int wv = t >> 6;
    const int lane = t & 63;
    const int wq = __builtin_amdgcn_readfirstlane(blockIdx.x * 4 + wv);  // query id
    const int b  = wq >> 13;
    const int qi = wq & (NPTS - 1);
    const float* base = pts + (size_t)b * (NPTS * 3);
    const unsigned* cs = cellStart + b * (NCELLS + 1);
    const float4* sp = sortedp + (size_t)b * NPTS;
    unsigned* sl = survl + wv * SSTRIDE;

    const float qx = base[qi * 3 + 0];   // wave-uniform scalar loads
    const float qy = base[qi * 3 + 1];
    const float qz = base[qi * 3 + 2];
    const float g2 = g2buf[wq];
    const float g  = sqrtf(g2);

    int ixlo = cidx(qx - g), ixhi = cidx(qx + g);
    int iylo = cidx(qy - g), iyhi = cidx(qy + g);
    int izlo = cidx(qz - g), izhi = cidx(qz + g);
    int nx = ixhi - ixlo + 1;
    int ny = iyhi - iylo + 1;
    int nyz = ny * (izhi - izlo + 1);
    const int lR  = (nyz >= 8) ? 3 : (nyz >= 4) ? 2 : (nyz >= 2) ? 1 : 0;
    const int R   = 1 << lR;
    const int lsl = 6 - lR;
    const unsigned SL = 64u >> lR;
    const unsigned slot = (unsigned)lane & (SL - 1u);
    unsigned cnt = 0;                          // wave-uniform by construction
    #pragma unroll 1
    for (int r0 = 0; r0 < nyz; r0 += 64) {
        int r = r0 + lane;
        unsigned pk = 0;
        if (r < nyz) {
            int iz = izlo + r / ny;
            int iy = iylo + (r - (r / ny) * ny);
            int cb = (iz * NC + iy) * NC + ixlo;
            unsigned sB = cs[cb];
            pk = sB | ((cs[cb + nx] - sB) << 14);
        }
        int rmax = min(nyz - r0, 64);
        int gcount = (rmax + R - 1) >> lR;
        #pragma unroll 1
        for (int gg = 0; gg < gcount; ++gg) {
            unsigned pkm = __shfl(pk, (gg << lR) + (lane >> lsl), 64);
            unsigned sBm = pkm & 0x3FFFu;
            unsigned lm  = pkm >> 14;
            #pragma unroll 1
            for (unsigned st = slot; ; st += SL) {
                bool in = st < lm;
                if (!__any(in ? 1 : 0)) break;
                float4 c = sp[min(sBm + st, (unsigned)(NPTS - 1))];
                float dx = qx - c.x, dy = qy - c.y, dz = qz - c.z;
                float d2 = dx * dx + dy * dy + dz * dz;   // reference-form d2
                bool pass = in && (d2 < g2);
                unsigned long long m = __ballot(pass);
                if (pass) {
                    unsigned sw = min(cnt + mbcnt64(m), (unsigned)(SSTRIDE - 1));
                    sl[sw] = mkkey(d2, __float_as_uint(c.w));
                }
                cnt += (unsigned)__popcll(m);
            }
        }
    }

    // ---- in-wave top-16 selection ----
    bool valid = (cnt >= KNN) && (cnt <= 128u);   // radix covers 128 keys (2/lane)
    if (valid) {
        unsigned k0 = (lane < (int)cnt)      ? sl[lane]      : 0xFFFFFFFFu;
        unsigned k1 = (lane + 64 < (int)cnt) ? sl[lane + 64] : 0xFFFFFFFFu;
        // radix binary search: P ends as the exact 16th-smallest key
        unsigned P = 0;
        #pragma unroll 1
        for (int bit = 31; bit >= 0; --bit) {
            unsigned mid = P | (1u << bit);
            unsigned c = (unsigned)__popcll(__ballot(k0 < mid))
                       + (unsigned)__popcll(__ballot(k1 < mid));
            if (c < 16u) P = mid;      // 16th smallest >= mid
        }
        // margin check: all filtered-out points provably outside 16th bucket
        float upper = __uint_as_float((P & 0xFFFFE000u) + 0x2000u);
        valid = (upper < g2 * 0.999f - 1e-5f);
        if (valid) {
            bool sel0 = (k0 <= P);
            bool sel1 = (k1 <= P);
            unsigned long long m0 = __ballot(sel0);
            unsigned long long m1 = __ballot(sel1);
            unsigned base1 = (unsigned)__popcll(m0);
            if (sel0) sl[mbcnt64(m0)] = k0;           // exactly 16 selected total
            if (sel1) sl[base1 + mbcnt64(m1)] = k1;
            unsigned myk = sl[lane & 15];             // lanes 0-15 meaningful
            unsigned rnk = 0;
            #pragma unroll
            for (int j = 0; j < 16; ++j) {
                unsigned kj = __shfl(myk, j, 64);
                rnk += (kj < myk) ? 1u : 0u;
            }
            if (lane < 16)
                idx16[(size_t)wq * 32 + rnk] = myk & 0x1FFFu;   // ascending order
        }
    }
    if (!valid && lane == 0) {       // exact fallback (P ~ 1e-3/run at lambda=48)
        unsigned gl[KNN];
        #pragma unroll
        for (int m = 0; m < KNN; ++m) gl[m] = 0xFFFFFFFFu;
        #pragma unroll 1
        for (int i = 0; i < NPTS; ++i) {
            float cx = base[i * 3 + 0];
            float cy = base[i * 3 + 1];
            float cz = base[i * 3 + 2];
            float dx = qx - cx, dy = qy - cy, dz = qz - cz;
            float d2 = dx * dx + dy * dy + dz * dz;
            unsigned k = mkkey(d2, (unsigned)i);
            if (k < gl[KNN - 1]) insert16(k, gl);
        }
        unsigned* dst = idx16 + (size_t)wq * 32;
        #pragma unroll
        for (int m = 0; m < KNN; ++m) dst[m] = gl[m] & 0x1FFFu;
    }
}

// Patch kNN: 64 queries/block (quarter patch), 4 lanes/query x 64 patch pts,
// gated bubble insert + butterfly merge4 (verbatim).
__global__ void __launch_bounds__(256)
pselect_kernel(const float* __restrict__ pts, unsigned* __restrict__ idx16)
{
    __shared__ float4 pbuf4[PTCH];                 // 4 KB own patch
    const int t = threadIdx.x;
    const int w = t >> 6;
    const int lane = t & 63;
    const int p = blockIdx.x;
    const int quarter = blockIdx.y;
    const int b = blockIdx.z;
    const float* base = pts + (size_t)b * (NPTS * 3);

    {
        const float* src = base + p * (PTCH * 3);
        float* dst = (float*)pbuf4;
        #pragma unroll
        for (int s = 0; s < 3; ++s) {
            int f = t + s * 256;
            int j = f / 3;
            int c = f - 3 * j;
            dst[j * 4 + c] = src[f];
        }
    }
    __syncthreads();

    const int qq = lane >> 2;            // 0..15
    const int h = lane & 3;
    const int qlocal = quarter * 64 + w * 16 + qq;   // 0..255 within patch
    float4 qv = pbuf4[qlocal];
    const float pqx = qv.x, pqy = qv.y, pqz = qv.z;

    unsigned pl[KNN];
    #pragma unroll
    for (int m = 0; m < KNN; ++m) pl[m] = 0xFFFFFFFFu;
    const int j0 = h * 64;
    #pragma unroll 4
    for (int j = j0; j < j0 + 64; ++j) {
        float4 c = pbuf4[j];
        float dx = pqx - c.x, dy = pqy - c.y, dz = pqz - c.z;
        float d2 = dx * dx + dy * dy + dz * dz;
        unsigned k = mkkey(d2, (unsigned)j);
        if (k < pl[KNN - 1]) insert16(k, pl);
    }
    merge4(pl, lane);
    if (h == 0) {
        int qid = b * NPTS + p * PTCH + qlocal;
        unsigned* dst = idx16 + (size_t)qid * 32 + 16;   // type 1 = patch
        #pragma unroll
        for (int m = 0; m < KNN; ++m)
            dst[m] = (unsigned)(p * PTCH) + (pl[m] & 0x1FFFu);
    }
}

// 1 thread per eig (65536 = 32768 queries x {global,patch}); full-lane fp64.
__global__ void __launch_bounds__(256)
eig_loss_kernel(const float* __restrict__ pts,
                const unsigned* __restrict__ idx16,
                double* __restrict__ partials)
{
    __shared__ double sln[4], slv[4];
    const int t = threadIdx.x;
    const int e = blockIdx.x * 256 + t;     // 0..65535
    const int qid = e >> 1;
    const int b = qid >> 13;
    const int qi = qid & (NPTS - 1);
    const float* base = pts + (size_t)b * (NPTS * 3);

    const double qxd = (double)base[qi * 3 + 0];
    const double qyd = (double)base[qi * 3 + 1];
    const double qzd = (double)base[qi * 3 + 2];

    const unsigned* L = idx16 + (size_t)qid * 32 + (e & 1) * 16;
    double c00 = 0, c11 = 0, c22 = 0, c01 = 0, c02 = 0, c12 = 0;
    #pragma unroll
    for (int m = 0; m < KNN; ++m) {
        int idx = (int)L[m];
        double dx = (double)base[idx * 3 + 0] - qxd;
        double dy = (double)base[idx * 3 + 1] - qyd;
        double dz = (double)base[idx * 3 + 2] - qzd;
        c00 += dx * dx; c11 += dy * dy; c22 += dz * dz;
        c01 += dx * dy; c02 += dx * dz; c12 += dy * dz;
    }
    double nx, ny, nz, lmin, lsum;
    eig3(c00, c11, c22, c01, c02, c12, nx, ny, nz, lmin, lsum);
    double sv = lmin / lsum;

    double onx = __shfl_xor(nx, 1, 64);
    double ony = __shfl_xor(ny, 1, 64);
    double onz = __shfl_xor(nz, 1, 64);
    double osv = __shfl_xor(sv, 1, 64);

    double ln = 0.0, lsv = 0.0;
    if ((e & 1) == 0) {          // even lane: own = global, partner = patch
        double dx = fabs(onx) - fabs(nx);
        double dy = fabs(ony) - fabs(ny);
        double dz = fabs(onz) - fabs(nz);
        ln  = sqrt(dx * dx + dy * dy + dz * dz);
        double ds = osv - sv;
        lsv = ds * ds;
    }
    #pragma unroll
    for (int o = 32; o > 0; o >>= 1) {
        ln  += __shfl_down(ln, o);
        lsv += __shfl_down(lsv, o);
    }
    const int w = t >> 6;
    if ((t & 63) == 0) { sln[w] = ln; slv[w] = lsv; }
    __syncthreads();
    if (t == 0) {
        partials[blockIdx.x * 2 + 0] = sln[0] + sln[1] + sln[2] + sln[3];
        partials[blockIdx.x * 2 + 1] = slv[0] + slv[1] + slv[2] + slv[3];
    }
}

// 1 block: deterministic fixed-order double sum of 256 partial pairs.
__global__ void __launch_bounds__(256)
reduce_kernel(const double* __restrict__ partials, float* __restrict__ out)
{
    __shared__ double sln[4], slv[4];
    const int t = threadIdx.x;
    double a = partials[t * 2 + 0];
    double c = partials[t * 2 + 1];
    #pragma unroll
    for (int o = 32; o > 0; o >>= 1) {
        a += __shfl_down(a, o);
        c += __shfl_down(c, o);
    }
    if ((t & 63) == 0) { sln[t >> 6] = a; slv[t >> 6] = c; }
    __syncthreads();
    if (t == 0) {
        const double inv = 1.0 / (double)(NBATCH * NPTS);
        out[0] = (float)((sln[0] + sln[1] + sln[2] + sln[3]) * inv);
        out[1] = (float)((slv[0] + slv[1] + slv[2] + slv[3]) * inv);
    }
}

extern "C" void kernel_launch(void* const* d_in, const int* in_sizes, int n_in,
                              void* d_out, int out_size, void* d_ws, size_t ws_size,
                              hipStream_t stream)
{
    const float* pts = (const float*)d_in[0];
    float* out = (float*)d_out;

    // workspace carve-up (16B-aligned), ~4.9 MB total:
    //   cellStart @ 0       : 4*4097*4   = 65552
    //   sorted    @ 65552   : 4*8192*16  = 524288  -> 589840
    //   g2buf     @ 589840  : 32768*4    = 131072  -> 720912
    //   idx16     @ 720912  : 32768*32*4 = 4194304 -> 4915216
    //   partials  @ 4915216 : 256*2*8    = 4096    -> 4919312
    unsigned char* ws = (unsigned char*)d_ws;
    unsigned* cellStart = (unsigned*)(ws);
    float4*   sorted    = (float4*)  (ws + 65552);
    float*    g2buf     = (float*)   (ws + 589840);
    unsigned* idx16     = (unsigned*)(ws + 720912);
    double*   partials  = (double*)  (ws + 4915216);

    hipLaunchKernelGGL(build_kernel, dim3(NBATCH), dim3(BT), 0, stream,
                       pts, out, cellStart, sorted);
    hipLaunchKernelGGL(gate_kernel, dim3(NBATCH * NPTS / 256), dim3(256), 0, stream,
                       pts, g2buf);
    hipLaunchKernelGGL(fselect_kernel, dim3(NBATCH * NPTS / 4), dim3(256), 0, stream,
                       pts, g2buf, cellStart, sorted, idx16);
    hipLaunchKernelGGL(pselect_kernel, dim3(NPATCH, 4, NBATCH), dim3(256), 0, stream,
                       pts, idx16);
    hipLaunchKernelGGL(eig_loss_kernel, dim3(NBATCH * NPTS * 2 / 256), dim3(256),
                       0, stream, pts, idx16, partials);
    hipLaunchKernelGGL(reduce_kernel, dim3(1), dim3(256), 0, stream,
                       partials, out);
}